// Round 1
// baseline (498.243 us; speedup 1.0000x reference)
//
#include <hip/hip_runtime.h>
#include <math.h>
#include <float.h>

#define N_BATCH 256
#define C_IN    3
#define D_IN    32
#define HW_IN   32
#define C_OUT   24
#define KS      3
#define D_OUTS  30
#define HW_OUT  30
#define TH      8     // output h-rows per block

// Transpose weights (C_OUT,C_IN,K,K,K) -> wt[tap][c] with tap=((ci*3+kd)*3+kh)*3+kw.
// Makes the inner channel loop read 24 consecutive wave-uniform dwords (s_load_dwordx8).
__global__ void prep_weights(const float* __restrict__ w, float* __restrict__ wt) {
    int i = blockIdx.x * blockDim.x + threadIdx.x;  // over 81*24
    if (i < 81 * C_OUT) {
        int tap = i / C_OUT;
        int c   = i - tap * C_OUT;
        wt[i] = w[c * 81 + tap];
    }
}

__global__ __launch_bounds__(256) void conv3d_min_softmax(
    const float* __restrict__ x, const float* __restrict__ wt,
    const float* __restrict__ bias, float* __restrict__ out)
{
    // 3-deep ring of input depth slices: [phase][ci][h0..h0+9][w 0..31]
    __shared__ float lds[3][C_IN][TH + 2][32];

    const int tid = threadIdx.x;
    const int w   = tid & 31;          // output w lane (active if < 30)
    const int ty  = tid >> 5;          // output h row within tile
    const int bid = blockIdx.x;
    const int n   = bid >> 2;
    const int ht  = bid & 3;
    const int h0  = ht * TH;
    const int h   = h0 + ty;
    const bool active = (w < HW_OUT) && (h < HW_OUT);

    // Stage depth slice d (3 ci x up-to-10 rows x 32 w) into lds[d%3] via float4.
    auto stage = [&](int d) {
        if (tid < 240) {
            int ci  = tid / 80;
            int rem = tid - ci * 80;
            int row = rem >> 3;
            int c4  = rem & 7;
            int gh  = h0 + row;
            if (gh < HW_IN) {
                const float4 v = *reinterpret_cast<const float4*>(
                    &x[(((size_t)(n * C_IN + ci) * D_IN + d) * HW_IN + gh) * HW_IN + c4 * 4]);
                *reinterpret_cast<float4*>(&lds[d % 3][ci][row][c4 * 4]) = v;
            }
        }
    };

    float mn[C_OUT];
#pragma unroll
    for (int c = 0; c < C_OUT; ++c) mn[c] = FLT_MAX;

    stage(0);
    stage(1);

    for (int dd = 0; dd < D_OUTS; ++dd) {
        stage(dd + 2);
        __syncthreads();
        if (active) {
            float acc[C_OUT];
#pragma unroll
            for (int c = 0; c < C_OUT; ++c) acc[c] = bias[c];
#pragma unroll
            for (int kd = 0; kd < KS; ++kd) {
                const int ph = (dd + kd) % 3;
#pragma unroll
                for (int ci = 0; ci < C_IN; ++ci) {
#pragma unroll
                    for (int kh = 0; kh < KS; ++kh) {
#pragma unroll
                        for (int kw = 0; kw < KS; ++kw) {
                            const float xv = lds[ph][ci][ty + kh][w + kw];
                            const int tap = ((ci * 3 + kd) * 3 + kh) * 3 + kw;
#pragma unroll
                            for (int c = 0; c < C_OUT; ++c)
                                acc[c] = fmaf(wt[tap * C_OUT + c], xv, acc[c]);
                        }
                    }
                }
            }
#pragma unroll
            for (int c = 0; c < C_OUT; ++c) mn[c] = fminf(mn[c], acc[c]);
        }
        __syncthreads();
    }

    if (active) {
        float m = mn[0];
#pragma unroll
        for (int c = 1; c < C_OUT; ++c) m = fmaxf(m, mn[c]);
        float s = 0.f;
        float e[C_OUT];
#pragma unroll
        for (int c = 0; c < C_OUT; ++c) { e[c] = expf(mn[c] - m); s += e[c]; }
        const float inv = 1.0f / s;
#pragma unroll
        for (int c = 0; c < C_OUT; ++c)
            out[((size_t)(n * C_OUT + c) * HW_OUT + h) * HW_OUT + w] = e[c] * inv;
    }
}

extern "C" void kernel_launch(void* const* d_in, const int* in_sizes, int n_in,
                              void* d_out, int out_size, void* d_ws, size_t ws_size,
                              hipStream_t stream) {
    const float* x    = (const float*)d_in[0];
    const float* wgt  = (const float*)d_in[1];
    const float* bias = (const float*)d_in[2];
    float* out = (float*)d_out;
    float* wt  = (float*)d_ws;   // 81*24*4 = 7776 bytes of scratch

    prep_weights<<<dim3((81 * C_OUT + 255) / 256), 256, 0, stream>>>(wgt, wt);
    conv3d_min_softmax<<<dim3(N_BATCH * 4), 256, 0, stream>>>(x, wt, bias, out);
}